// Round 2
// baseline (469.128 us; speedup 1.0000x reference)
//
#include <hip/hip_runtime.h>

// PostNormBoth: T=256-step recurrence, B=512 chains, H=256.
// R3: 8 rows per block (64 blocks x 512 threads, wave==row).
//  - MFMA matvec amortized over 8 batch rows (8 of 16 B-columns real):
//    515 cyc/SIMD-step covers 8 rows instead of 1-2.
//  - 4 hidden columns per thread: per-thread loop overhead amortized 4x.
//  - memory slot array moved to a static 134MB __device__ buffer (L3-resident);
//    admit value prefetched 1 step early; first-lap reads are t<61 -> 0, so no
//    zero-init needed and the buffer is multi-launch safe.
//  - LN stats fully in-wave (DPP + ds_swizzle xor16 + shfl xor32): no LDS
//    round trip, no stats barrier. 2 barriers/step total.
//  - raw s_barrier + lgkmcnt(0) only (no vmcnt(0) drain): the global
//    prefetch stays in flight across barriers. g_mem is same-thread-only,
//    so skipping vmcnt at barriers is safe.

#define TT 256
#define NROW 8
#define NBLK 64

typedef __bf16 bf16x8 __attribute__((ext_vector_type(8)));
typedef __bf16 bf16x4 __attribute__((ext_vector_type(4)));
typedef float  f32x4  __attribute__((ext_vector_type(4)));

// [block][slot 64][row 8][hid 256] f32 = 134 MB
__device__ float g_mem[(size_t)NBLK * 64 * NROW * 256];

__device__ __forceinline__ float fast_tanh(float x) {
    float e = __expf(2.f * x);
    return 1.f - __fdividef(2.f, e + 1.f);
}

// v += dpp(v); old=0 + bound_ctrl so masked lanes add 0.
template<int CTRL, int RM>
__device__ __forceinline__ float dpp_add(float v) {
    int t = __builtin_amdgcn_update_dpp(0, __float_as_int(v), CTRL, RM, 0xf, true);
    return v + __int_as_float(t);
}

// 64-lane sum, result valid in ALL lanes.
__device__ __forceinline__ float wave_sum_all(float v) {
    v = dpp_add<0xB1,  0xf>(v);   // xor1 (quad_perm)
    v = dpp_add<0x4E,  0xf>(v);   // xor2 (quad_perm)
    v = dpp_add<0x141, 0xf>(v);   // 8-group (half mirror)
    v = dpp_add<0x140, 0xf>(v);   // 16-group (row mirror)
    {   int t = __builtin_amdgcn_ds_swizzle(__float_as_int(v), 0x401F); // xor16
        v += __int_as_float(t); }
    v += __shfl_xor(v, 32, 64);   // xor32
    return v;
}

// raw barrier: drain LDS only, leave vmcnt (global prefetch) in flight.
#define BAR() do { \
    asm volatile("s_waitcnt lgkmcnt(0)" ::: "memory"); \
    __builtin_amdgcn_s_barrier(); \
    asm volatile("" ::: "memory"); \
} while (0)

// ---- dynamic LDS layout (bytes) ----
// s_y   [8][260] f32 :     0  (8320)
// s_x   [8][256] f32 :  8320  (8192)
// s_v   [8][264] bf16: 16512  (4224)
// s_wt  [64][8]  f32 : 20736  (2048)
// s_oacc[80]     f32 : 22784  (320)
#define SMEM_BYTES 23104

__global__ __launch_bounds__(512, 2)
void postnorm_kernel(const float* __restrict__ x,
                     const float* __restrict__ W_embed,
                     const float* __restrict__ b_embed,
                     const float* __restrict__ W_update,
                     const float* __restrict__ b_update,
                     const float* __restrict__ gamma,
                     const float* __restrict__ beta,
                     const float* __restrict__ W_out,
                     const float* __restrict__ b_out,
                     const float* __restrict__ ctx_s,
                     float* __restrict__ out)
{
    extern __shared__ __align__(16) char smem[];
    float*  s_y    = (float*)(smem);
    float*  s_x    = (float*)(smem + 8320);
    __bf16* s_v    = (__bf16*)(smem + 16512);
    float*  s_wt   = (float*)(smem + 20736);
    float*  s_oacc = (float*)(smem + 22784);

    const int tid  = threadIdx.x;
    const int wave = tid >> 6;     // batch row AND M-tile owner
    const int lane = tid & 63;
    const int bn   = lane & 15;    // MFMA A-row-in-tile / D col (batch row)
    const int q    = lane >> 4;
    const int row  = wave;
    const int h0   = lane << 2;    // 4 hidden columns per thread
    const int r0   = blockIdx.x * NROW;

    // ---- init ----
    ((f32x4*)s_x)[tid] = ((const f32x4*)(x + r0 * TT))[tid];   // 2048 floats
    if (tid < 80) s_oacc[tid] = 0.f;

    // weight table: pointer is t&63; row padded to 8 floats
    if (tid < 64) {
        float wv[5]; float ssum = 0.f;
        #pragma unroll
        for (int k = 0; k < 5; ++k) {
            int idx = (tid + k - 2) & 63;
            float d = (float)idx - (float)tid;
            wv[k] = expf(-(d * d) * 0.125f);   // TAU=8
            ssum += wv[k];
        }
        #pragma unroll
        for (int k = 0; k < 5; ++k) s_wt[tid * 8 + k] = wv[k] / ssum;
    }

    // per-hid params (4 each)
    const f32x4 we = *(const f32x4*)(W_embed  + h0);
    const f32x4 be = *(const f32x4*)(b_embed  + h0);
    const f32x4 bu = *(const f32x4*)(b_update + h0);
    const f32x4 gm = *(const f32x4*)(gamma    + h0);
    const f32x4 bt = *(const f32x4*)(beta     + h0);
    const float csv = 1.f / (1.f + expf(-ctx_s[0]));

    // ---- W_update -> bf16 MFMA A-fragments (32 M-rows per wave) ----
    bf16x8 wfa[2][8];
    #pragma unroll
    for (int mt = 0; mt < 2; ++mt) {
        #pragma unroll
        for (int kt = 0; kt < 8; ++kt) {
            const float* wp = W_update + (wave * 32 + mt * 16 + bn) * 256
                                       + kt * 32 + q * 8;
            f32x4 a = *(const f32x4*)wp;
            f32x4 b = *(const f32x4*)(wp + 4);
            bf16x8 f;
            f[0] = (__bf16)a[0]; f[1] = (__bf16)a[1];
            f[2] = (__bf16)a[2]; f[3] = (__bf16)a[3];
            f[4] = (__bf16)b[0]; f[5] = (__bf16)b[1];
            f[6] = (__bf16)b[2]; f[7] = (__bf16)b[3];
            wfa[mt][kt] = f;
        }
    }

    BAR();   // x, wt table visible

    // v(t=0): memory==0, h==0 -> v = inp
    {
        float xv = s_x[row * TT];
        bf16x4 vv;
        #pragma unroll
        for (int j = 0; j < 4; ++j)
            vv[j] = (__bf16)fast_tanh(xv * we[j] + be[j]);
        *(bf16x4*)(s_v + row * 264 + h0) = vv;
    }
    // pointer-0 attention weights
    float wt0 = s_wt[0], wt1 = s_wt[1], wt2 = s_wt[2], wt3 = s_wt[3], wt4 = s_wt[4];

    BAR();   // v visible

    const __bf16* vs = s_v + (bn & 7) * 264 + q * 8;   // bn>=8 duplicates row bn-8
    float* mbase = g_mem + (size_t)blockIdx.x * (64 * NROW * 256) + row * 256 + h0;

    f32x4 z4 = {0.f, 0.f, 0.f, 0.f};
    f32x4 wr0 = z4, wr1 = z4, wr2 = z4, wr3 = z4, wr4 = z4;   // sliding window
    f32x4 nf  = z4;                                            // prefetched admit
    f32x4 hn  = z4;

    #pragma unroll 1
    for (int t = 0; t < TT; ++t) {
        // next-step weights + x (broadcast reads; hide under MFMA)
        const float* wp = s_wt + ((t + 1) & 63) * 8;
        f32x4 nw = *(const f32x4*)wp;
        float nw4 = wp[4];
        float xn = s_x[row * TT + ((t + 1) & 255)];

        // --- P1: y[j,r] = sum_i W[j,i] v[r,i] via MFMA (cols 0..7 real) ---
        f32x4 a0 = z4, a1 = z4;
        #pragma unroll
        for (int kt = 0; kt < 8; ++kt) {
            bf16x8 bfr = *(const bf16x8*)(vs + kt * 32);
            a0 = __builtin_amdgcn_mfma_f32_16x16x32_bf16(wfa[0][kt], bfr, a0, 0, 0, 0);
            a1 = __builtin_amdgcn_mfma_f32_16x16x32_bf16(wfa[1][kt], bfr, a1, 0, 0, 0);
        }
        if (bn < NROW) {               // D: row = q*4+reg, col = bn
            float* yb = s_y + bn * 260 + wave * 32 + q * 4;
            *(f32x4*)yb        = a0;
            *(f32x4*)(yb + 16) = a1;
        }
        BAR();

        // --- P2: bias + tanh + in-wave LN stats ---
        f32x4 yv = *(const f32x4*)(s_y + row * 260 + h0);
        f32x4 yt;
        #pragma unroll
        for (int j = 0; j < 4; ++j) yt[j] = fast_tanh(yv[j] + bu[j]);
        float ps1 = (yt[0] + yt[1]) + (yt[2] + yt[3]);
        float ps2 = (yt[0]*yt[0] + yt[1]*yt[1]) + (yt[2]*yt[2] + yt[3]*yt[3]);
        float S1 = wave_sum_all(ps1);
        float S2 = wave_sum_all(ps2);
        float mu   = S1 * (1.f / 256.f);
        float var  = S2 * (1.f / 256.f) - mu * mu;
        float rstd = rsqrtf(var + 1e-5f);
        #pragma unroll
        for (int j = 0; j < 4; ++j) hn[j] = (yt[j] - mu) * rstd * gm[j] + bt[j];

        // --- P3: scatter + slide + context + next v ---
        #pragma unroll
        for (int j = 0; j < 4; ++j) {
            wr0[j] += wt0 * hn[j]; wr1[j] += wt1 * hn[j]; wr2[j] += wt2 * hn[j];
            wr3[j] += wt3 * hn[j]; wr4[j] += wt4 * hn[j];
        }
        if (t < TT - 1) {
            // retire slot (t-2)&63 to global
            *(f32x4*)(mbase + ((t - 2) & 63) * (NROW * 256)) = wr0;
            // slide window; admit slot t+3 (prefetched last step, 0 for t<61)
            wr0 = wr1; wr1 = wr2; wr2 = wr3; wr3 = wr4; wr4 = nf;
            bf16x4 vv;
            #pragma unroll
            for (int j = 0; j < 4; ++j) {
                float ctx = ((nw[0] * wr0[j] + nw[1] * wr1[j])
                           + (nw[2] * wr2[j] + nw[3] * wr3[j])) + nw4 * wr4[j];
                float inp = fast_tanh(xn * we[j] + be[j]);
                vv[j] = (__bf16)(inp + csv * ctx + hn[j]);
            }
            *(bf16x4*)(s_v + row * 264 + h0) = vv;
            wt0 = nw[0]; wt1 = nw[1]; wt2 = nw[2]; wt3 = nw[3]; wt4 = nw4;
        }
        // prefetch admit value for step t+1 (slot (t+4)&63); covers BAR+P1+P2
        if (t >= 60 && t <= 253)
            nf = *(const f32x4*)(mbase + ((t + 4) & 63) * (NROW * 256));
        else
            nf = z4;
        BAR();
    }

    // --- epilogue: out[r0+row, o] = h . W_out[o,:] + b_out[o] ---
    #pragma unroll
    for (int o = 0; o < 10; ++o) {
        f32x4 wo = *(const f32x4*)(W_out + o * 256 + h0);
        float p = (hn[0] * wo[0] + hn[1] * wo[1]) + (hn[2] * wo[2] + hn[3] * wo[3]);
        #pragma unroll
        for (int m = 32; m >= 1; m >>= 1) p += __shfl_xor(p, m, 64);
        if (lane == 0) s_oacc[row * 10 + o] = p;
    }
    BAR();
    if (tid < 80) {
        int rr = tid / 10, o = tid % 10;
        out[(r0 + rr) * 10 + o] = s_oacc[tid] + b_out[o];
    }
}

extern "C" void kernel_launch(void* const* d_in, const int* in_sizes, int n_in,
                              void* d_out, int out_size, void* d_ws, size_t ws_size,
                              hipStream_t stream) {
    const float* x    = (const float*)d_in[0];
    const float* W_e  = (const float*)d_in[1];
    const float* b_e  = (const float*)d_in[2];
    const float* W_u  = (const float*)d_in[3];
    const float* b_u  = (const float*)d_in[4];
    const float* gmm  = (const float*)d_in[5];
    const float* bta  = (const float*)d_in[6];
    const float* W_o  = (const float*)d_in[7];
    const float* b_o  = (const float*)d_in[8];
    const float* cst  = (const float*)d_in[9];
    float* out = (float*)d_out;

    postnorm_kernel<<<dim3(NBLK), dim3(512), SMEM_BYTES, stream>>>(
        x, W_e, b_e, W_u, b_u, gmm, bta, W_o, b_o, cst, out);
}

// Round 3
// 327.251 us; speedup vs baseline: 1.4335x; 1.4335x over previous
//
#include <hip/hip_runtime.h>

// PostNormBoth: T=256-step recurrence, B=512 independent chains, H=256.
// R4 = R1 structure (256 blocks x 512 threads, 2 rows/block, LDS memory
// slots, 3 barriers/step) + targeted stall fixes:
//  - s_v row stride 264 -> 288 bf16 (576B = 64 mod 128B): row1 B-frags hit
//    banks 16-31 vs row0's 0-15 -> kills the 2.1e7 conflict cycles.
//  - admit load (nf), next-step weights (nw) and next x (xn) prefetched
//    BEFORE the loop-end barrier: the barrier drain covers their latency
//    instead of them sitting on the P3 critical path.
//  - input tanh hoisted to the top of the step (hidden under MFMA phase).
//  - tail branch dropped (final-step stores are harmless).

#define TT 256

typedef __bf16 bf16x8 __attribute__((ext_vector_type(8)));
typedef float  f32x4  __attribute__((ext_vector_type(4)));

__device__ __forceinline__ float fast_tanh(float x) {
    float e = __expf(2.f * x);
    return 1.f - __fdividef(2.f, e + 1.f);
}

// v += dpp(v); CTRL/RM compile-time. old=0 + bound_ctrl so masked lanes add 0.
template<int CTRL, int RM>
__device__ __forceinline__ float dpp_add(float v) {
    int t = __builtin_amdgcn_update_dpp(0, __float_as_int(v), CTRL, RM, 0xf, true);
    return v + __int_as_float(t);
}
// full 64-lane sum; valid in lane 63.
__device__ __forceinline__ float wave_sum63(float v) {
    v = dpp_add<0xB1,  0xf>(v);   // quad_perm xor1
    v = dpp_add<0x4E,  0xf>(v);   // quad_perm xor2
    v = dpp_add<0x141, 0xf>(v);   // row_half_mirror (8-group)
    v = dpp_add<0x140, 0xf>(v);   // row_mirror (16-group)
    v = dpp_add<0x142, 0xa>(v);   // row_bcast15 -> rows 1,3
    v = dpp_add<0x143, 0xc>(v);   // row_bcast31 -> rows 2,3
    return v;
}

// ---- dynamic LDS layout (bytes) ----
// s_mem  [2][64][256] f32 :      0  (131072)
// s_x    [2][256]     f32 : 131072  (2048)
// s_y    [2][256]     f32 : 133120  (2048)
// s_v    [2][288]     bf16: 135168  (1152)
// s_red1 [8]          f32 : 136320  (32)
// s_red2 [8]          f32 : 136352  (32)
// s_wt   [64][8]      f32 : 136384  (2048)
// s_oacc [20]         f32 : 138432  (80)
#define SMEM_BYTES 138512

__global__ __launch_bounds__(512, 2)
void postnorm_kernel(const float* __restrict__ x,
                     const float* __restrict__ W_embed,
                     const float* __restrict__ b_embed,
                     const float* __restrict__ W_update,
                     const float* __restrict__ b_update,
                     const float* __restrict__ gamma,
                     const float* __restrict__ beta,
                     const float* __restrict__ W_out,
                     const float* __restrict__ b_out,
                     const float* __restrict__ ctx_s,
                     float* __restrict__ out)
{
    extern __shared__ __align__(16) char smem[];
    float*  s_mem  = (float*)(smem);
    float*  s_x    = (float*)(smem + 131072);
    float*  s_y    = (float*)(smem + 133120);
    __bf16* s_v    = (__bf16*)(smem + 135168);
    float*  s_red1 = (float*)(smem + 136320);
    float*  s_red2 = (float*)(smem + 136352);
    float*  s_wt   = (float*)(smem + 136384);
    float*  s_oacc = (float*)(smem + 138432);

    const int tid  = threadIdx.x;
    const int n    = tid >> 8;      // batch row within block (0..1)
    const int i    = tid & 255;     // hidden index
    const int wave = tid >> 6;      // wave w owns W rows [32w,32w+32)
    const int lane = tid & 63;
    const int bn   = lane & 15;     // MFMA col; real batch only for <2
    const int quad = lane >> 4;
    const int r0   = blockIdx.x * 2;

    // ---- init ----
    {   f32x4 z = {0.f, 0.f, 0.f, 0.f};
        f32x4* p = (f32x4*)s_mem;
        #pragma unroll
        for (int k = 0; k < 16; ++k) p[tid + k * 512] = z;
    }
    s_x[tid] = x[(r0 + n) * TT + i];
    if (tid < 20) s_oacc[tid] = 0.f;

    // weight table: pointer is t&63 for all rows; row padded to 8 floats
    if (tid < 64) {
        float wv[5]; float ssum = 0.f;
        #pragma unroll
        for (int k = 0; k < 5; ++k) {
            int idx = (tid + k - 2) & 63;            // wrapped index
            float d = (float)idx - (float)tid;       // delta AFTER wrap
            wv[k] = expf(-(d * d) * 0.125f);         // TAU=8
            ssum += wv[k];
        }
        #pragma unroll
        for (int k = 0; k < 5; ++k) s_wt[tid * 8 + k] = wv[k] / ssum;
    }

    const float we  = W_embed[i];
    const float be  = b_embed[i];
    const float bu  = b_update[i];
    const float gm  = gamma[i];
    const float btt = beta[i];
    const float csv = 1.f / (1.f + expf(-ctx_s[0]));

    // ---- W_update -> bf16 MFMA A-fragments resident in VGPRs ----
    bf16x8 wfa[2][8];
    #pragma unroll
    for (int mt = 0; mt < 2; ++mt) {
        #pragma unroll
        for (int kt = 0; kt < 8; ++kt) {
            const float* wp = W_update + (wave * 32 + mt * 16 + bn) * 256
                                       + kt * 32 + quad * 8;
            f32x4 a = *(const f32x4*)wp;
            f32x4 b = *(const f32x4*)(wp + 4);
            bf16x8 f;
            f[0] = (__bf16)a[0]; f[1] = (__bf16)a[1];
            f[2] = (__bf16)a[2]; f[3] = (__bf16)a[3];
            f[4] = (__bf16)b[0]; f[5] = (__bf16)b[1];
            f[6] = (__bf16)b[2]; f[7] = (__bf16)b[3];
            wfa[mt][kt] = f;
        }
    }

    __syncthreads();
    {   // v(t=0): memory==0, h==0 -> v = inp
        float inp0 = fast_tanh(s_x[n * 256] * we + be);
        s_v[n * 288 + i] = (__bf16)inp0;
    }

    // attention weights for pointer 0 + prefetched step-0 P3 inputs
    float wt0, wt1, wt2, wt3, wt4;
    {   f32x4 wv = *(const f32x4*)(s_wt);
        wt0 = wv[0]; wt1 = wv[1]; wt2 = wv[2]; wt3 = wv[3]; wt4 = s_wt[4];
    }
    f32x4 nw  = *(const f32x4*)(s_wt + 8);       // weights for pointer 1
    float nw4 = s_wt[8 + 4];
    float xn  = s_x[n * 256 + 1];                // x[t+1]
    float nf  = 0.f;                             // admit slot 3 (zero-init)
    __syncthreads();

    float hn = 0.f;
    // register window: slots (t-2..t+2) mod 64 of memory column (n,i)
    float w0 = 0.f, w1 = 0.f, w2 = 0.f, w3 = 0.f, w4 = 0.f;
    float* mcol = s_mem + (n << 14) + i;
    // broadcast B-frag source; row stride 288 bf16 = 576B -> banks disjoint
    const __bf16* vsrc = s_v + (bn & 1) * 288 + quad * 8;

    #pragma unroll 1
    for (int t = 0; t < TT; ++t) {
        // input embed for v(t+1): independent of this step -> hides under P1
        float inp = fast_tanh(xn * we + be);

        // --- P1: y[j,n] = sum_i W[j,i] v[n,i] via MFMA ---
        f32x4 a0a = {0,0,0,0}, a0b = {0,0,0,0}, a1a = {0,0,0,0}, a1b = {0,0,0,0};
        #pragma unroll
        for (int kt = 0; kt < 4; ++kt) {
            bf16x8 bfr0 = *(const bf16x8*)(vsrc + kt * 32);
            bf16x8 bfr1 = *(const bf16x8*)(vsrc + (kt + 4) * 32);
            a0a = __builtin_amdgcn_mfma_f32_16x16x32_bf16(wfa[0][kt],     bfr0, a0a, 0, 0, 0);
            a1a = __builtin_amdgcn_mfma_f32_16x16x32_bf16(wfa[1][kt],     bfr0, a1a, 0, 0, 0);
            a0b = __builtin_amdgcn_mfma_f32_16x16x32_bf16(wfa[0][kt + 4], bfr1, a0b, 0, 0, 0);
            a1b = __builtin_amdgcn_mfma_f32_16x16x32_bf16(wfa[1][kt + 4], bfr1, a1b, 0, 0, 0);
        }
        if (bn < 2) {                 // D: row = quad*4+reg, col = bn
            f32x4 y0 = a0a + a0b, y1 = a1a + a1b;
            float* yb = s_y + bn * 256 + wave * 32 + quad * 4;
            *(f32x4*)yb        = y0;
            *(f32x4*)(yb + 16) = y1;
        }
        __syncthreads();

        // --- P2: bias + tanh + LN stats via DPP ---
        float yt = fast_tanh(s_y[tid] + bu);
        float s1 = wave_sum63(yt);
        float s2 = wave_sum63(yt * yt);
        if (lane == 63) { s_red1[wave] = s1; s_red2[wave] = s2; }
        __syncthreads();

        // --- P3: LN finalize + register-window scatter/gather ---
        f32x4 r1 = *(const f32x4*)(s_red1 + n * 4);
        f32x4 r2 = *(const f32x4*)(s_red2 + n * 4);
        float S1 = (r1[0] + r1[1]) + (r1[2] + r1[3]);
        float S2 = (r2[0] + r2[1]) + (r2[2] + r2[3]);
        float mu   = S1 * (1.f / 256.f);
        float var  = S2 * (1.f / 256.f) - mu * mu;
        float rstd = rsqrtf(var + 1e-5f);
        hn = (yt - mu) * rstd * gm + btt;

        // scatter with pointer-t weights (positional: w0 = slot t-2)
        w0 += wt0 * hn; w1 += wt1 * hn; w2 += wt2 * hn;
        w3 += wt3 * hn; w4 += wt4 * hn;

        // slide window: retire slot t-2, admit slot t+3 (prefetched)
        mcol[((t - 2) & 63) << 8] = w0;
        w0 = w1; w1 = w2; w2 = w3; w3 = w4; w4 = nf;
        float ctx = ((nw[0] * w0 + nw[1] * w1) + (nw[2] * w2 + nw[3] * w3))
                  + nw4 * w4;
        float v = inp + csv * ctx + hn;
        s_v[n * 288 + i] = (__bf16)v;
        wt0 = nw[0]; wt1 = nw[1]; wt2 = nw[2]; wt3 = nw[3]; wt4 = nw4;

        // prefetch next step's P3 inputs; loop-end barrier drain covers
        // their latency. mcol slot (t+4)&63 is same-thread-only (last
        // written at step t-58, next write at t+6) -> no cross-thread hazard.
        nf  = mcol[((t + 4) & 63) << 8];
        {   const float* wp = s_wt + ((t + 2) & 63) * 8;
            nw  = *(const f32x4*)wp;
            nw4 = wp[4];
        }
        xn  = s_x[n * 256 + ((t + 2) & 255)];
        __syncthreads();
    }

    // --- epilogue: out[r0+n, o] = h . W_out[o,:] + b_out[o] ---
    #pragma unroll
    for (int o = 0; o < 10; ++o) {
        float p = hn * W_out[o * 256 + i];
        #pragma unroll
        for (int m = 32; m >= 1; m >>= 1) p += __shfl_xor(p, m, 64);
        if (lane == 0) atomicAdd(&s_oacc[n * 10 + o], p);
    }
    __syncthreads();
    if (tid < 20) {
        int nn = tid / 10, o = tid % 10;
        out[(r0 + nn) * 10 + o] = s_oacc[tid] + b_out[o];
    }
}

extern "C" void kernel_launch(void* const* d_in, const int* in_sizes, int n_in,
                              void* d_out, int out_size, void* d_ws, size_t ws_size,
                              hipStream_t stream) {
    const float* x    = (const float*)d_in[0];
    const float* W_e  = (const float*)d_in[1];
    const float* b_e  = (const float*)d_in[2];
    const float* W_u  = (const float*)d_in[3];
    const float* b_u  = (const float*)d_in[4];
    const float* gmm  = (const float*)d_in[5];
    const float* bta  = (const float*)d_in[6];
    const float* W_o  = (const float*)d_in[7];
    const float* b_o  = (const float*)d_in[8];
    const float* cst  = (const float*)d_in[9];
    float* out = (float*)d_out;

    (void)hipFuncSetAttribute(reinterpret_cast<const void*>(postnorm_kernel),
                              hipFuncAttributeMaxDynamicSharedMemorySize,
                              SMEM_BYTES);

    postnorm_kernel<<<dim3(256), dim3(512), SMEM_BYTES, stream>>>(
        x, W_e, b_e, W_u, b_u, gmm, bta, W_o, b_o, cst, out);
}